// Round 11
// baseline (143.388 us; speedup 1.0000x reference)
//
#include <hip/hip_runtime.h>

#define Nn 768
#define Dd 128
#define LDP 136   // fallback-path padded bf16 row stride

typedef __attribute__((ext_vector_type(8))) short bf16x8;
typedef __attribute__((ext_vector_type(4))) float f32x4;
typedef __attribute__((ext_vector_type(4))) int   i32x4;

static __device__ __forceinline__ unsigned short f2bf(float f) {
  unsigned int u = __builtin_bit_cast(unsigned int, f);
  u += 0x7fffu + ((u >> 16) & 1u);   // RNE
  return (unsigned short)(u >> 16);
}
static __device__ __forceinline__ float bf2f(unsigned short h) {
  unsigned int u = ((unsigned int)h) << 16;
  return __builtin_bit_cast(float, u);
}
// packed f32 pair -> [bf16(hi):bf16(lo)] in one VALU op (RNE)
static __device__ __forceinline__ unsigned int cvtpk(float lo, float hi) {
  unsigned int r;
  asm("v_cvt_pk_bf16_f32 %0, %1, %2" : "=v"(r) : "v"(lo), "v"(hi));
  return r;
}

// ---------------- fast path ----------------
// k_prep: per i, compute l_i (dot-products), write left bf16 AND
// B_all[i][e][d] = bf16(W_out[e][d] * l_i[d])  (coalesced dwordx4 stores).
__global__ __launch_bounds__(256)
void k_prep(const float* __restrict__ x, const float* __restrict__ Win,
            const float* __restrict__ bin, const float* __restrict__ Wout,
            unsigned short* __restrict__ left, unsigned short* __restrict__ B_all) {
  __shared__ float sx[Dd];
  __shared__ float sL[Dd];
  const int i = blockIdx.x;
  const int t = threadIdx.x;

  if (t < Dd) sx[t] = x[i * Dd + t];
  __syncthreads();

  if (t < Dd) {
    const float4* wrow = (const float4*)(Win + t * Dd);
    float a0 = 0.f, a1 = 0.f, a2 = 0.f, a3 = 0.f;
#pragma unroll
    for (int d4 = 0; d4 < Dd / 4; d4 += 4) {
      float4 w0 = wrow[d4+0], w1 = wrow[d4+1], w2 = wrow[d4+2], w3 = wrow[d4+3];
      a0 += sx[4*d4+ 0]*w0.x + sx[4*d4+ 1]*w0.y + sx[4*d4+ 2]*w0.z + sx[4*d4+ 3]*w0.w;
      a1 += sx[4*d4+ 4]*w1.x + sx[4*d4+ 5]*w1.y + sx[4*d4+ 6]*w1.z + sx[4*d4+ 7]*w1.w;
      a2 += sx[4*d4+ 8]*w2.x + sx[4*d4+ 9]*w2.y + sx[4*d4+10]*w2.z + sx[4*d4+11]*w2.w;
      a3 += sx[4*d4+12]*w3.x + sx[4*d4+13]*w3.y + sx[4*d4+14]*w3.z + sx[4*d4+15]*w3.w;
    }
    const float v = ((a0 + a1) + (a2 + a3)) + bin[t];
    sL[t] = v;
    left[i * Dd + t] = f2bf(v);
  }
  __syncthreads();

  // B_i rows: thread t -> row r = t>>1, 64 cols from c0. Wave covers 32 rows
  // x 256 B contiguous -> coalesced 16B stores.
  {
    const int r  = t >> 1;
    const int c0 = (t & 1) * 64;
    const float4* wp = (const float4*)(Wout + r * Dd + c0);
    unsigned short* brow = B_all + (size_t)i * (Dd * Dd) + r * Dd + c0;
    const float* lp = sL + c0;
#pragma unroll
    for (int q = 0; q < 8; ++q) {       // 8 elems per iter
      float4 w0 = wp[2*q], w1 = wp[2*q+1];
      i32x4 vb;
      vb[0] = (int)cvtpk(w0.x * lp[8*q+0], w0.y * lp[8*q+1]);
      vb[1] = (int)cvtpk(w0.z * lp[8*q+2], w0.w * lp[8*q+3]);
      vb[2] = (int)cvtpk(w1.x * lp[8*q+4], w1.y * lp[8*q+5]);
      vb[3] = (int)cvtpk(w1.z * lp[8*q+6], w1.w * lp[8*q+7]);
      *(i32x4*)(brow + q * 8) = vb;
    }
  }
}

// k_outer_pure: zero LDS, zero barriers, zero staging VALU. A from left
// (L2-hot), B from B_all (L2/L3-hot). All loads precede all stores.
__global__ __launch_bounds__(256, 4)
void k_outer_pure(const unsigned short* __restrict__ left,
                  const unsigned short* __restrict__ B_all,
                  const float* __restrict__ bout, float* __restrict__ out) {
  const int jt = blockIdx.x;   // 0..5
  const int i  = blockIdx.y;   // 0..767
  const int t  = threadIdx.x;  // 0..255

  const int wid  = t >> 6;        // wave 0..3 -> j rows [wid*32, wid*32+32)
  const int lane = t & 63;
  const int l15  = lane & 15;
  const int koct = (lane >> 4) * 8;

  float bias[8];
#pragma unroll
  for (int n = 0; n < 8; ++n) bias[n] = bout[n * 16 + l15];

  const unsigned short* gA = left + (size_t)(jt * 128 + wid * 32 + l15) * Dd + koct;
  const unsigned short* gB = B_all + (size_t)i * (Dd * Dd) + l15 * Dd + koct;

  f32x4 acc[2][8] = {};   // [j-frag][e-chunk]
#pragma unroll
  for (int kb = 0; kb < 4; ++kb) {
    bf16x8 a0 = *(const bf16x8*)(gA + kb * 32);
    bf16x8 a1 = *(const bf16x8*)(gA + 16 * Dd + kb * 32);
#pragma unroll
    for (int n = 0; n < 8; ++n) {
      bf16x8 b = *(const bf16x8*)(gB + n * 16 * Dd + kb * 32);
      acc[0][n] = __builtin_amdgcn_mfma_f32_16x16x32_bf16(a0, b, acc[0][n], 0, 0, 0);
      acc[1][n] = __builtin_amdgcn_mfma_f32_16x16x32_bf16(a1, b, acc[1][n], 0, 0, 0);
    }
  }

  // R9-proven epilogue: row(j) = (lane>>4)*4 + r, col(e) = n*16 + l15.
#pragma unroll
  for (int jb = 0; jb < 2; ++jb) {
#pragma unroll
    for (int r = 0; r < 4; ++r) {
      const int j = jt * 128 + wid * 32 + jb * 16 + (lane >> 4) * 4 + r;
      float* orow = out + ((size_t)i * Nn + j) * Dd;
#pragma unroll
      for (int n = 0; n < 8; ++n) {
        orow[n * 16 + l15] = acc[jb][n][r] + bias[n];
      }
    }
  }
}

// ---------------- fallback path (R9, proven 62.3us) ----------------
__global__ __launch_bounds__(128)
void k_left(const float* __restrict__ x, const float* __restrict__ Win,
            const float* __restrict__ bin, unsigned short* __restrict__ left) {
  __shared__ float sx[Dd];
  const int i = blockIdx.x;
  const int e = threadIdx.x;
  sx[e] = x[i * Dd + e];
  __syncthreads();
  const float4* wrow = (const float4*)(Win + e * Dd);
  float a0 = 0.f, a1 = 0.f, a2 = 0.f, a3 = 0.f;
#pragma unroll
  for (int d4 = 0; d4 < Dd / 4; d4 += 4) {
    float4 w0 = wrow[d4+0], w1 = wrow[d4+1], w2 = wrow[d4+2], w3 = wrow[d4+3];
    a0 += sx[4*d4+ 0]*w0.x + sx[4*d4+ 1]*w0.y + sx[4*d4+ 2]*w0.z + sx[4*d4+ 3]*w0.w;
    a1 += sx[4*d4+ 4]*w1.x + sx[4*d4+ 5]*w1.y + sx[4*d4+ 6]*w1.z + sx[4*d4+ 7]*w1.w;
    a2 += sx[4*d4+ 8]*w2.x + sx[4*d4+ 9]*w2.y + sx[4*d4+10]*w2.z + sx[4*d4+11]*w2.w;
    a3 += sx[4*d4+12]*w3.x + sx[4*d4+13]*w3.y + sx[4*d4+14]*w3.z + sx[4*d4+15]*w3.w;
  }
  left[i * Dd + e] = f2bf(((a0 + a1) + (a2 + a3)) + bin[e]);
}

__global__ __launch_bounds__(256, 4)
void k_outer_r9(const unsigned short* __restrict__ left, const float* __restrict__ Wout,
                const float* __restrict__ bout, float* __restrict__ out) {
  __shared__ __attribute__((aligned(16))) unsigned short sB[128 * LDP];
  __shared__ float sLi[Dd];
  __shared__ float sBo[Dd];

  const int jt = blockIdx.x;
  const int i  = blockIdx.y;
  const int t  = threadIdx.x;

  if (t < Dd) { sLi[t] = bf2f(left[i * Dd + t]); sBo[t] = bout[t]; }
  __syncthreads();
  {
    const int row = t >> 4;
    const int c8  = (t & 15) * 8;
    float l[8];
#pragma unroll
    for (int q = 0; q < 8; ++q) l[q] = sLi[c8 + q];
#pragma unroll
    for (int it = 0; it < 8; ++it) {
      const int r = row + it * 16;
      const float4* wp = (const float4*)(Wout + r * Dd + c8);
      float4 w0 = wp[0], w1 = wp[1];
      i32x4 vb;
      vb[0] = (int)cvtpk(w0.x * l[0], w0.y * l[1]);
      vb[1] = (int)cvtpk(w0.z * l[2], w0.w * l[3]);
      vb[2] = (int)cvtpk(w1.x * l[4], w1.y * l[5]);
      vb[3] = (int)cvtpk(w1.z * l[6], w1.w * l[7]);
      *(i32x4*)(sB + r * LDP + c8) = vb;
    }
  }
  __syncthreads();

  const int wid  = t >> 6;
  const int lane = t & 63;
  const int l15  = lane & 15;
  const int kq   = (lane >> 4) * 8;

  float bias[8];
#pragma unroll
  for (int n = 0; n < 8; ++n) bias[n] = sBo[n * 16 + l15];

  const unsigned short* gA = left + (size_t)(jt * 128 + wid * 32 + l15) * Dd;
  bf16x8 A0[4], A1[4];
#pragma unroll
  for (int kb = 0; kb < 4; ++kb) {
    A0[kb] = *(const bf16x8*)(gA + kb * 32 + kq);
    A1[kb] = *(const bf16x8*)(gA + 16 * Dd + kb * 32 + kq);
  }

  f32x4 acc[2][8] = {};
#pragma unroll
  for (int n = 0; n < 8; ++n) {
    const unsigned short* sBrow = sB + (n * 16 + l15) * LDP + kq;
#pragma unroll
    for (int kb = 0; kb < 4; ++kb) {
      bf16x8 b = *(const bf16x8*)(sBrow + kb * 32);
      acc[0][n] = __builtin_amdgcn_mfma_f32_16x16x32_bf16(A0[kb], b, acc[0][n], 0, 0, 0);
      acc[1][n] = __builtin_amdgcn_mfma_f32_16x16x32_bf16(A1[kb], b, acc[1][n], 0, 0, 0);
    }
  }
#pragma unroll
  for (int jb = 0; jb < 2; ++jb) {
#pragma unroll
    for (int r = 0; r < 4; ++r) {
      const int j = jt * 128 + wid * 32 + jb * 16 + (lane >> 4) * 4 + r;
      float* orow = out + ((size_t)i * Nn + j) * Dd;
#pragma unroll
      for (int n = 0; n < 8; ++n) {
        orow[n * 16 + l15] = acc[jb][n][r] + bias[n];
      }
    }
  }
}

extern "C" void kernel_launch(void* const* d_in, const int* in_sizes, int n_in,
                              void* d_out, int out_size, void* d_ws, size_t ws_size,
                              hipStream_t stream) {
  const float* x    = (const float*)d_in[0];
  const float* Win  = (const float*)d_in[1];
  const float* bin  = (const float*)d_in[2];
  const float* Wout = (const float*)d_in[3];
  const float* bout = (const float*)d_in[4];
  float* out = (float*)d_out;

  const size_t NEED = 262144 + (size_t)Nn * Dd * Dd * 2;   // left + B_all = 25.4 MB
  dim3 grid(Nn / 128, Nn);
  if (ws_size >= NEED) {
    unsigned short* left  = (unsigned short*)d_ws;
    unsigned short* B_all = (unsigned short*)((char*)d_ws + 262144);
    k_prep<<<Nn, 256, 0, stream>>>(x, Win, bin, Wout, left, B_all);
    k_outer_pure<<<grid, 256, 0, stream>>>(left, B_all, bout, out);
  } else {
    unsigned short* left = (unsigned short*)d_ws;
    k_left<<<Nn, Dd, 0, stream>>>(x, Win, bin, left);
    k_outer_r9<<<grid, 256, 0, stream>>>(left, Wout, bout, out);
  }
}

// Round 12
// 85.849 us; speedup vs baseline: 1.6702x; 1.6702x over previous
//
#include <hip/hip_runtime.h>

#define Nn 768
#define Dd 128

typedef __attribute__((ext_vector_type(8))) short bf16x8;
typedef __attribute__((ext_vector_type(4))) float f32x4;
typedef __attribute__((ext_vector_type(4))) int   i32x4;

static __device__ __forceinline__ unsigned short f2bf(float f) {
  unsigned int u = __builtin_bit_cast(unsigned int, f);
  u += 0x7fffu + ((u >> 16) & 1u);   // RNE
  return (unsigned short)(u >> 16);
}
// packed f32 pair -> [bf16(hi):bf16(lo)] in one VALU op (RNE)
static __device__ __forceinline__ unsigned int cvtpk(float lo, float hi) {
  unsigned int r;
  asm("v_cvt_pk_bf16_f32 %0, %1, %2" : "=v"(r) : "v"(lo), "v"(hi));
  return r;
}

// left[i][e] = sum_d x[i][d] * W_in[e][d] + b_in[e]; bf16 copy + f32 copy.
__global__ __launch_bounds__(128)
void k_left(const float* __restrict__ x, const float* __restrict__ Win,
            const float* __restrict__ bin, unsigned short* __restrict__ left,
            float* __restrict__ left_f) {
  __shared__ float sx[Dd];
  const int i = blockIdx.x;
  const int e = threadIdx.x;
  sx[e] = x[i * Dd + e];
  __syncthreads();
  const float4* wrow = (const float4*)(Win + e * Dd);
  float a0 = 0.f, a1 = 0.f, a2 = 0.f, a3 = 0.f;
#pragma unroll
  for (int d4 = 0; d4 < Dd / 4; d4 += 4) {
    float4 w0 = wrow[d4+0], w1 = wrow[d4+1], w2 = wrow[d4+2], w3 = wrow[d4+3];
    a0 += sx[4*d4+ 0]*w0.x + sx[4*d4+ 1]*w0.y + sx[4*d4+ 2]*w0.z + sx[4*d4+ 3]*w0.w;
    a1 += sx[4*d4+ 4]*w1.x + sx[4*d4+ 5]*w1.y + sx[4*d4+ 6]*w1.z + sx[4*d4+ 7]*w1.w;
    a2 += sx[4*d4+ 8]*w2.x + sx[4*d4+ 9]*w2.y + sx[4*d4+10]*w2.z + sx[4*d4+11]*w2.w;
    a3 += sx[4*d4+12]*w3.x + sx[4*d4+13]*w3.y + sx[4*d4+14]*w3.z + sx[4*d4+15]*w3.w;
  }
  const float v = ((a0 + a1) + (a2 + a3)) + bin[e];
  left_f[i * Dd + e] = v;
  left[i * Dd + e]   = f2bf(v);
}

// out[i, j, e] = sum_d left[j][d] * (W_out[e][d]*left[i][d]) + b_out[e]
// R9 skeleton squeezed to 5 blocks/CU (20 waves): sB unpadded 32 KiB with
// XOR swizzle (byte ^= (row&7)<<4), no sLi/sBo (left_f / bout read direct),
// kb-outer MFMA loop for low VGPR. LDS 5*32768 = 160 KiB exactly.
__global__ __launch_bounds__(256, 5)
void k_outer(const unsigned short* __restrict__ left,
             const float* __restrict__ left_f,
             const float* __restrict__ Wout,
             const float* __restrict__ bout, float* __restrict__ out) {
  __shared__ __attribute__((aligned(16))) unsigned short sB[128 * 128];

  const int jt = blockIdx.x;   // 0..5
  const int i  = blockIdx.y;   // 0..767
  const int t  = threadIdx.x;  // 0..255

  // ---- stage sB = bf16(Wout[e][:] * l_i[:]) swizzled, no barrier before:
  // thread t covers col-chunk c8=(t&15)*8 x rows (t>>4)+16k.
  {
    const int c8 = (t & 15) * 8;
    const int r0 = t >> 4;
    const int wsw = ((r0 & 7) << 4);          // row&7 == r0&7 (step 16)
    const float4* lfp = (const float4*)(left_f + i * Dd + c8);
    float4 f0 = lfp[0], f1 = lfp[1];
    char* sBb = (char*)sB;
#pragma unroll
    for (int it = 0; it < 8; ++it) {
      const int r = r0 + it * 16;             // 0..127
      const float4* wp = (const float4*)(Wout + r * Dd + c8);
      float4 w0 = wp[0], w1 = wp[1];
      i32x4 vb;
      vb[0] = (int)cvtpk(w0.x * f0.x, w0.y * f0.y);
      vb[1] = (int)cvtpk(w0.z * f0.z, w0.w * f0.w);
      vb[2] = (int)cvtpk(w1.x * f1.x, w1.y * f1.y);
      vb[3] = (int)cvtpk(w1.z * f1.z, w1.w * f1.w);
      *(i32x4*)(sBb + r * 256 + ((c8 * 2) ^ wsw)) = vb;
    }
  }
  __syncthreads();

  const int wid  = t >> 6;        // wave 0..3 -> j rows [wid*32, wid*32+32)
  const int lane = t & 63;
  const int l15  = lane & 15;
  const int kq   = (lane >> 4) * 8;         // k-octet (elems)
  const int rsw  = ((l15 & 7) << 4);        // read swizzle: row&7 == l15&7

  float bias[8];
#pragma unroll
  for (int n = 0; n < 8; ++n) bias[n] = bout[n * 16 + l15];

  const unsigned short* gA = left + (size_t)(jt * 128 + wid * 32 + l15) * Dd + kq;
  const char* sBb = (const char*)sB;

  f32x4 acc[2][8] = {};   // [j-frag][e-chunk]
#pragma unroll
  for (int kb = 0; kb < 4; ++kb) {
    bf16x8 a0 = *(const bf16x8*)(gA + kb * 32);
    bf16x8 a1 = *(const bf16x8*)(gA + 16 * Dd + kb * 32);
    const int cb = (kb * 64 + kq * 2) ^ rsw;   // swizzled col-byte
#pragma unroll
    for (int n = 0; n < 8; ++n) {
      bf16x8 b = *(const bf16x8*)(sBb + (n * 16 + l15) * 256 + cb);
      acc[0][n] = __builtin_amdgcn_mfma_f32_16x16x32_bf16(a0, b, acc[0][n], 0, 0, 0);
      acc[1][n] = __builtin_amdgcn_mfma_f32_16x16x32_bf16(a1, b, acc[1][n], 0, 0, 0);
    }
  }

  // R9-proven epilogue: row(j) = (lane>>4)*4 + r, col(e) = n*16 + l15.
#pragma unroll
  for (int jb = 0; jb < 2; ++jb) {
#pragma unroll
    for (int r = 0; r < 4; ++r) {
      const int j = jt * 128 + wid * 32 + jb * 16 + (lane >> 4) * 4 + r;
      float* orow = out + ((size_t)i * Nn + j) * Dd;
#pragma unroll
      for (int n = 0; n < 8; ++n) {
        orow[n * 16 + l15] = acc[jb][n][r] + bias[n];
      }
    }
  }
}

extern "C" void kernel_launch(void* const* d_in, const int* in_sizes, int n_in,
                              void* d_out, int out_size, void* d_ws, size_t ws_size,
                              hipStream_t stream) {
  const float* x    = (const float*)d_in[0];
  const float* Win  = (const float*)d_in[1];
  const float* bin  = (const float*)d_in[2];
  const float* Wout = (const float*)d_in[3];
  const float* bout = (const float*)d_in[4];
  float* out = (float*)d_out;
  unsigned short* left   = (unsigned short*)d_ws;                 // 192 KiB bf16
  float*          left_f = (float*)((char*)d_ws + 256 * 1024);    // 384 KiB f32

  k_left<<<Nn, Dd, 0, stream>>>(x, Win, bin, left, left_f);
  dim3 grid(Nn / 128, Nn);
  k_outer<<<grid, 256, 0, stream>>>(left, left_f, Wout, bout, out);
}

// Round 13
// 63.618 us; speedup vs baseline: 2.2539x; 1.3494x over previous
//
#include <hip/hip_runtime.h>

#define Nn 768
#define Dd 128
#define LDP 136   // padded bf16 row stride (272 B)

typedef __attribute__((ext_vector_type(8))) short bf16x8;
typedef __attribute__((ext_vector_type(4))) float f32x4;
typedef __attribute__((ext_vector_type(4))) int   i32x4;

static __device__ __forceinline__ unsigned short f2bf(float f) {
  unsigned int u = __builtin_bit_cast(unsigned int, f);
  u += 0x7fffu + ((u >> 16) & 1u);   // RNE
  return (unsigned short)(u >> 16);
}
static __device__ __forceinline__ float bf2f(unsigned short h) {
  unsigned int u = ((unsigned int)h) << 16;
  return __builtin_bit_cast(float, u);
}
// packed f32 pair -> [bf16(hi):bf16(lo)] in one VALU op (RNE)
static __device__ __forceinline__ unsigned int cvtpk(float lo, float hi) {
  unsigned int r;
  asm("v_cvt_pk_bf16_f32 %0, %1, %2" : "=v"(r) : "v"(lo), "v"(hi));
  return r;
}

// left[i][e] = sum_d x[i][d] * W_in[e][d] + b_in[e], stored bf16
__global__ __launch_bounds__(128)
void k_left(const float* __restrict__ x, const float* __restrict__ Win,
            const float* __restrict__ bin, unsigned short* __restrict__ left) {
  __shared__ float sx[Dd];
  const int i = blockIdx.x;
  const int e = threadIdx.x;
  sx[e] = x[i * Dd + e];
  __syncthreads();
  const float4* wrow = (const float4*)(Win + e * Dd);
  float a0 = 0.f, a1 = 0.f, a2 = 0.f, a3 = 0.f;
#pragma unroll
  for (int d4 = 0; d4 < Dd / 4; d4 += 4) {
    float4 w0 = wrow[d4+0], w1 = wrow[d4+1], w2 = wrow[d4+2], w3 = wrow[d4+3];
    a0 += sx[4*d4+ 0]*w0.x + sx[4*d4+ 1]*w0.y + sx[4*d4+ 2]*w0.z + sx[4*d4+ 3]*w0.w;
    a1 += sx[4*d4+ 4]*w1.x + sx[4*d4+ 5]*w1.y + sx[4*d4+ 6]*w1.z + sx[4*d4+ 7]*w1.w;
    a2 += sx[4*d4+ 8]*w2.x + sx[4*d4+ 9]*w2.y + sx[4*d4+10]*w2.z + sx[4*d4+11]*w2.w;
    a3 += sx[4*d4+12]*w3.x + sx[4*d4+13]*w3.y + sx[4*d4+14]*w3.z + sx[4*d4+15]*w3.w;
  }
  left[i * Dd + e] = f2bf(((a0 + a1) + (a2 + a3)) + bin[e]);
}

// out[i, j, e] = sum_d left[j][d] * (W_out[e][d]*left[i][d]) + b_out[e]
// R9 structure at 512 threads / 8 waves: each wave owns 16j x 128e ->
// acc = 32 VGPR, A-preload 16 VGPR; launch_bounds(512,6) -> 24 waves/CU
// (3 blocks, LDS 107.5 KB). Single barrier pair; issue-and-forget stores.
__global__ __launch_bounds__(512, 6)
void k_outer(const unsigned short* __restrict__ left, const float* __restrict__ Wout,
             const float* __restrict__ bout, float* __restrict__ out) {
  __shared__ __attribute__((aligned(16))) unsigned short sB[128 * LDP]; // Wout[e][d]*l_i[d]
  __shared__ float sLi[Dd];
  __shared__ float sBo[Dd];

  const int jt = blockIdx.x;   // 0..5
  const int i  = blockIdx.y;   // 0..767
  const int t  = threadIdx.x;  // 0..511

  if (t < Dd) {
    sLi[t] = bf2f(left[i * Dd + t]);
    sBo[t] = bout[t];
  }
  __syncthreads();

  // Stage sB (cvt_pk packing): thread covers col-chunk c8 x 4 rows (step 32).
  {
    const int row = t >> 4;          // 0..31
    const int c8  = (t & 15) * 8;
    float l[8];
#pragma unroll
    for (int q = 0; q < 8; ++q) l[q] = sLi[c8 + q];
#pragma unroll
    for (int it = 0; it < 4; ++it) {
      const int r = row + it * 32;   // 0..127
      const float4* wp = (const float4*)(Wout + r * Dd + c8);
      float4 w0 = wp[0], w1 = wp[1];
      i32x4 vb;
      vb[0] = (int)cvtpk(w0.x * l[0], w0.y * l[1]);
      vb[1] = (int)cvtpk(w0.z * l[2], w0.w * l[3]);
      vb[2] = (int)cvtpk(w1.x * l[4], w1.y * l[5]);
      vb[3] = (int)cvtpk(w1.z * l[6], w1.w * l[7]);
      *(i32x4*)(sB + r * LDP + c8) = vb;
    }
  }
  __syncthreads();

  const int wid  = t >> 6;        // wave 0..7 -> j rows [wid*16, wid*16+16)
  const int lane = t & 63;
  const int l15  = lane & 15;
  const int kq   = (lane >> 4) * 8;

  float bias[8];
#pragma unroll
  for (int n = 0; n < 8; ++n) bias[n] = sBo[n * 16 + l15];

  // Preload this wave's 4 A-fragments (left is L2/L3-hot, 192 KB).
  const unsigned short* gA = left + (size_t)(jt * 128 + wid * 16 + l15) * Dd;
  bf16x8 A[4];
#pragma unroll
  for (int kb = 0; kb < 4; ++kb) A[kb] = *(const bf16x8*)(gA + kb * 32 + kq);

  f32x4 acc[8] = {};   // [e-chunk]
#pragma unroll
  for (int n = 0; n < 8; ++n) {
    const unsigned short* sBrow = sB + (n * 16 + l15) * LDP + kq;
#pragma unroll
    for (int kb = 0; kb < 4; ++kb) {
      bf16x8 b = *(const bf16x8*)(sBrow + kb * 32);
      acc[n] = __builtin_amdgcn_mfma_f32_16x16x32_bf16(A[kb], b, acc[n], 0, 0, 0);
    }
  }

  // Proven epilogue: row(j) = (lane>>4)*4 + r, col(e) = n*16 + l15. Plain stores.
#pragma unroll
  for (int r = 0; r < 4; ++r) {
    const int j = jt * 128 + wid * 16 + (lane >> 4) * 4 + r;
    float* orow = out + ((size_t)i * Nn + j) * Dd;
#pragma unroll
    for (int n = 0; n < 8; ++n) {
      orow[n * 16 + l15] = acc[n][r] + bias[n];
    }
  }
}

extern "C" void kernel_launch(void* const* d_in, const int* in_sizes, int n_in,
                              void* d_out, int out_size, void* d_ws, size_t ws_size,
                              hipStream_t stream) {
  const float* x    = (const float*)d_in[0];
  const float* Win  = (const float*)d_in[1];
  const float* bin  = (const float*)d_in[2];
  const float* Wout = (const float*)d_in[3];
  const float* bout = (const float*)d_in[4];
  float* out = (float*)d_out;
  unsigned short* left = (unsigned short*)d_ws;  // 768*128 bf16 = 192 KiB

  k_left<<<Nn, Dd, 0, stream>>>(x, Win, bin, left);
  dim3 grid(Nn / 128, Nn);
  k_outer<<<grid, 512, 0, stream>>>(left, Wout, bout, out);
}